// Round 7
// baseline (1183.066 us; speedup 1.0000x reference)
//
#include <hip/hip_runtime.h>

// VQ-VAE VectorQuantizer forward + EMA update, MI355X (gfx950).
// Distance argmin bit-exactly emulates the numpy fp32 reference:
//   dist = pairwise_sum(x*x) - 2*(sgemm single-FMA-chain) + pairwise_sum(w*w)
// R2-R8 history: 128x128 scalar-FMA tiles plateau at 810-830us. Diagnosis:
//   8x8 tile needs 16 LDS floats per 64 FMAs -> 34.4GB LDS delivery = 437us
//   LDS-pipe wall == 437us FMA wall; two saturated pipes, imperfect overlap.
//   (pk_fma neutral: fp32 peak is 157TF scalar already; R8 confirmed.)
// R9: A-side moved to SGPRs. Wave owns 8 rows (row-uniform): A = scalar
//   loads from z (SMEM pipe, no LDS, no VALU, v_fma takes SGPR src0).
//   Lane owns 4 codes; block = 4 waves x 8 rows x 256 codes x full D.
//   Per dd: 1 ds_read_b128 per 32 FMAs -> LDS wall ~330us (not binding).
//   Barriers 64 -> 16. z consumed row-major -> zT transpose DELETED.
//   Chain per (row,code) = single fp32 FMA chain, d=0..255 ascending;
//   dist ops and tie-break comparator unchanged => bit-exact argmin.

#define NTOK 16384
#define KC   8192
#define DD   256

#define OFF_Q    0
#define OFF_LOSS 4194304
#define OFF_IDX  4194305
#define OFF_W    4210689
#define OFF_CS   6307841
#define OFF_EMA  6316033

#define DECAY_F  0.99f
#define OMD_F    0.01f
#define EPS_F    1e-5f
#define KEPS_F   0.08192f   // K * eps

#define SPLITC   32         // code chunks of 256

typedef __attribute__((address_space(3))) unsigned int lds_u;
typedef const __attribute__((address_space(1))) unsigned int glob_u;

// ---------------- 32x32 LDS transpose (coalesced both sides) ---------------
__global__ __launch_bounds__(256) void k_tr(const float* __restrict__ in,
                                            float* __restrict__ outT,
                                            int R, int C) {
    __shared__ float s[32][33];
    const int tx = threadIdx.x & 31, ty = threadIdx.x >> 5;
    const int c0 = blockIdx.x * 32, r0 = blockIdx.y * 32;
    #pragma unroll
    for (int i = 0; i < 4; ++i)
        s[ty + i * 8][tx] = in[(size_t)(r0 + ty + i * 8) * C + c0 + tx];
    __syncthreads();
    #pragma unroll
    for (int i = 0; i < 4; ++i)
        outT[(size_t)(c0 + ty + i * 8) * R + r0 + tx] = s[tx][ty + i * 8];
}

// ---- numpy-pairwise row squared-norms (n=256): two 128 halves, 8 strided
// accumulators each, butterfly combine — bit-exact vs numpy pairwise sum.
__global__ __launch_bounds__(256) void k_rownorm(const float* __restrict__ a,
                                                 float* __restrict__ outn) {
    const int wave = threadIdx.x >> 6, lane = threadIdx.x & 63;
    const int row  = blockIdx.x * 16 + wave * 4 + (lane >> 4);
    const int p    = lane & 15;
    const int h    = p >> 3, j = p & 7;
    const float* base = a + row * DD + h * 128 + j;
    float v = base[0];
    float r = __fmul_rn(v, v);
    #pragma unroll
    for (int t = 1; t < 16; ++t) {
        v = base[8 * t];
        r = __fadd_rn(r, __fmul_rn(v, v));
    }
    r = __fadd_rn(r, __shfl_xor(r, 1));
    r = __fadd_rn(r, __shfl_xor(r, 2));
    r = __fadd_rn(r, __shfl_xor(r, 4));
    r = __fadd_rn(r, __shfl_xor(r, 8));
    if (p == 0) outn[row] = r;
}

// ---------------- argmin: scalar-A GEMM, 32 rows x 256 codes per block -----
// grid = 16384: cc = blockIdx&31 (code chunk; cc&7 ~ XCD: its wT chunks stay
// L2-resident), rb = blockIdx>>5. Wave wv owns rows rb*32+wv*8 .. +8 (A in
// SGPRs via uniform scalar loads of z); lane owns codes c0+l*4 .. +4 (B via
// one ds_read_b128 per dd). 16 d-steps, double-buffered Ws staging via
// global_load_lds, one __syncthreads per step.
// acc[r][j] = single fp32 FMA chain over d=0..255 ascending (BLAS-exact).
__global__ __launch_bounds__(256) void k_argmin(
        const float* __restrict__ z, const float* __restrict__ wT,
        const float* __restrict__ x2v, const float* __restrict__ w2v,
        float* __restrict__ vbuf, int* __restrict__ kbuf) {
    __shared__ float Ws[2][16][256];   // [buf][d][code] 2 x 16 KB

    const int tid  = threadIdx.x;
    const int cc   = blockIdx.x & 31;
    const int rb   = blockIdx.x >> 5;
    const int c0   = cc * 256;
    const int l    = tid & 63;
    const int wv   = tid >> 6;
    const int l4   = l * 4;
    // wave-uniform row base (readfirstlane => compiler proves uniformity,
    // A-loads become s_load on the scalar pipe)
    const int wvu  = __builtin_amdgcn_readfirstlane(wv);
    const int row0 = rb * 32 + wvu * 8;
    const float* __restrict__ zr = z + (size_t)row0 * DD;

    float acc[8][4];
    #pragma unroll
    for (int r = 0; r < 8; ++r)
        #pragma unroll
        for (int j = 0; j < 4; ++j) acc[r][j] = 0.0f;

    // stage d-step s into buffer b: wave wv stages d-rows [wv*4, wv*4+4)
    auto stage = [&](int s, int b) {
        const int d0 = s * 16;
        #pragma unroll
        for (int q = 0; q < 4; ++q) {
            const int r = wv * 4 + q;           // wave-uniform d-row 0..15
            const float* gw = wT + (size_t)(d0 + r) * KC + c0 + l4;
            __builtin_amdgcn_global_load_lds(
                (glob_u*)gw,
                (lds_u*)((char*)&Ws[b][0][0] + r * 1024 + l * 16), 16, 0, 0);
        }
    };

    stage(0, 0);
    __syncthreads();

    for (int s = 0; s < 16; ++s) {
        const int cur = s & 1;
        if (s + 1 < 16) stage(s + 1, cur ^ 1);   // prefetch next d-chunk

        #pragma unroll
        for (int g = 0; g < 4; ++g) {
            // uniform scalar A: 8 rows x 4 d (SGPRs, scalar pipe)
            float As[8][4];
            #pragma unroll
            for (int r = 0; r < 8; ++r)
                #pragma unroll
                for (int q = 0; q < 4; ++q)
                    As[r][q] = zr[r * DD + s * 16 + g * 4 + q];
            #pragma unroll
            for (int q = 0; q < 4; ++q) {
                const int dd = g * 4 + q;
                const float4 bv = *(const float4*)&Ws[cur][dd][l4];
                #pragma unroll
                for (int r = 0; r < 8; ++r) {
                    acc[r][0] = __fmaf_rn(As[r][q], bv.x, acc[r][0]);
                    acc[r][1] = __fmaf_rn(As[r][q], bv.y, acc[r][1]);
                    acc[r][2] = __fmaf_rn(As[r][q], bv.z, acc[r][2]);
                    acc[r][3] = __fmaf_rn(As[r][q], bv.w, acc[r][3]);
                }
            }
        }
        // drains the prefetch (vmcnt, issued before ~1k-cycle FMA phase)
        // and the LDS reads (lgkmcnt); releases buffers.
        __syncthreads();
    }

    // dist = (x2 - 2*xe) + w2, per-op fp32 rounding; explicit (==, k<)
    // tie-break == np.argmin first-occurrence (order-independent min).
    const float4 w2 = *(const float4*)&w2v[c0 + l4];
    #pragma unroll
    for (int r = 0; r < 8; ++r) {
        const float x2 = x2v[row0 + r];          // uniform scalar load
        float bv_ = 1e30f;
        int   bk_ = 0x7fffffff;
        #pragma unroll
        for (int j = 0; j < 4; ++j) {            // code ascending
            const int   code = c0 + l4 + j;
            const float w2j  = (j == 0) ? w2.x : (j == 1) ? w2.y
                             : (j == 2) ? w2.z : w2.w;
            const float dv   = __fadd_rn(
                __fsub_rn(x2, __fmul_rn(2.0f, acc[r][j])), w2j);
            if (dv < bv_ || (dv == bv_ && code < bk_)) { bv_ = dv; bk_ = code; }
        }
        // 64-lane butterfly (min, smallest-code tie-break: associative)
        #pragma unroll
        for (int off = 32; off; off >>= 1) {
            const float ov = __shfl_xor(bv_, off, 64);
            const int   ok = __shfl_xor(bk_, off, 64);
            if (ov < bv_ || (ov == bv_ && ok < bk_)) { bv_ = ov; bk_ = ok; }
        }
        if (l == 0) {
            vbuf[cc * NTOK + row0 + r] = bv_;
            kbuf[cc * NTOK + row0 + r] = bk_;
        }
    }
}

// ---------------- combine the 32 chunk-candidates per row ------------------
__global__ __launch_bounds__(256) void k_reduce(const float* __restrict__ vbuf,
                                                const int* __restrict__ kbuf,
                                                int* __restrict__ idx_ws,
                                                float* __restrict__ out) {
    const int r = blockIdx.x * 256 + threadIdx.x;
    float bv = vbuf[r];
    int   bk = kbuf[r];
    #pragma unroll
    for (int s = 1; s < SPLITC; ++s) {
        const float v = vbuf[s * NTOK + r];
        const int   k = kbuf[s * NTOK + r];
        if (v < bv || (v == bv && k < bk)) { bv = v; bk = k; }
    }
    idx_ws[r] = bk;
    out[OFF_IDX + r] = (float)bk;
}

// ---------------- init EMA outputs + zero loss accumulator -----------------
// (runs AFTER k_reduce: OFF_EMA region doubles as vbuf/kbuf scratch)
__global__ __launch_bounds__(256) void k_init(const float* __restrict__ emaw,
                                              const float* __restrict__ ecs,
                                              float* __restrict__ out,
                                              float* __restrict__ lossacc) {
    const int i = blockIdx.x * 256 + threadIdx.x;    // grid covers KC*DD = 2M
    out[OFF_EMA + i] = __fmul_rn(DECAY_F, emaw[i]);
    if (i < KC) out[OFF_CS + i] = __fmul_rn(DECAY_F, ecs[i]);
    if (i == 0) *lossacc = 0.0f;
}

// ---------------- gather quantized + loss partial + EMA scatter ------------
__global__ __launch_bounds__(256) void k_scatter(const float* __restrict__ z,
                                                 const float* __restrict__ w,
                                                 const int* __restrict__ idx_ws,
                                                 float* __restrict__ out,
                                                 float* __restrict__ lossacc) {
    const int n = blockIdx.x, d = threadIdx.x;
    const int k = idx_ws[n];
    const float zv   = z[n * DD + d];
    const float q    = w[k * DD + d];
    const float diff = __fsub_rn(q, zv);
    out[OFF_Q + n * DD + d] = __fadd_rn(zv, diff);   // straight-through value

    float s = __fmul_rn(diff, diff);
    #pragma unroll
    for (int off = 32; off; off >>= 1) s += __shfl_down(s, off, 64);
    __shared__ float ps[4];
    if ((d & 63) == 0) ps[d >> 6] = s;
    __syncthreads();
    if (d == 0) atomicAdd(lossacc, ps[0] + ps[1] + ps[2] + ps[3]);

    atomicAdd(&out[OFF_EMA + k * DD + d], __fmul_rn(OMD_F, zv));
    if (d == 0) atomicAdd(&out[OFF_CS + k], OMD_F);
}

// ---------------- n = sum(new_cluster_size); finalize loss -----------------
__global__ __launch_bounds__(256) void k_nsum(float* __restrict__ out,
                                              const float* __restrict__ lossacc,
                                              float* __restrict__ nsum) {
    const int t = threadIdx.x;
    float s = 0.0f;
    for (int i = t; i < KC; i += 256) s += out[OFF_CS + i];
    #pragma unroll
    for (int off = 32; off; off >>= 1) s += __shfl_down(s, off, 64);
    __shared__ float ps[4];
    if ((t & 63) == 0) ps[t >> 6] = s;
    __syncthreads();
    if (t == 0) {
        *nsum = ps[0] + ps[1] + ps[2] + ps[3];
        out[OFF_LOSS] = 1.25f * (*lossacc) / 4194304.0f;
    }
}

// ---------------- new_weight = new_ema_w / laplace(cluster_size) -----------
__global__ __launch_bounds__(256) void k_neww(float* __restrict__ out,
                                              const float* __restrict__ nsum) {
    const int k = blockIdx.x, d = threadIdx.x;
    const float n  = *nsum;
    const float cs = __fmul_rn(__fdiv_rn(__fadd_rn(out[OFF_CS + k], EPS_F),
                                         __fadd_rn(n, KEPS_F)), n);
    out[OFF_W + k * DD + d] = __fdiv_rn(out[OFF_EMA + k * DD + d], cs);
}

extern "C" void kernel_launch(void* const* d_in, const int* in_sizes, int n_in,
                              void* d_out, int out_size, void* d_ws, size_t ws_size,
                              hipStream_t stream) {
    const float* z    = (const float*)d_in[0];
    const float* w    = (const float*)d_in[1];
    const float* ecs  = (const float*)d_in[2];
    const float* emaw = (const float*)d_in[3];
    float* out = (float*)d_out;

    // small scratch in ws (same footprint that already passed)
    int*   idx_ws  = (int*)d_ws;                       // NTOK ints
    float* x2v     = (float*)d_ws + NTOK;              // NTOK floats
    float* w2v     = x2v + NTOK;                       // KC floats
    float* lossacc = w2v + KC;                         // 1 float
    float* nsum    = lossacc + 1;                      // 1 float

    // big scratch inside not-yet-final d_out regions:
    float* wT   = out + OFF_W;     // 8192x256 -> 256x8192 (8 MB)
    float* vbuf = out + OFF_EMA;                         // SPLITC*NTOK floats (2 MB)
    int*   kbuf = (int*)(out + OFF_EMA) + SPLITC * NTOK; // SPLITC*NTOK ints   (2 MB)

    k_tr     <<<dim3(8, 256),     256, 0, stream>>>(w, wT, KC, DD);
    k_rownorm<<<NTOK / 16,        256, 0, stream>>>(z, x2v);
    k_rownorm<<<KC / 16,          256, 0, stream>>>(w, w2v);
    k_argmin <<<SPLITC * (NTOK / 32), 256, 0, stream>>>(z, wT, x2v, w2v, vbuf, kbuf);
    k_reduce <<<NTOK / 256,       256, 0, stream>>>(vbuf, kbuf, idx_ws, out);
    k_init   <<<(KC * DD) / 256,  256, 0, stream>>>(emaw, ecs, out, lossacc);
    k_scatter<<<NTOK,             256, 0, stream>>>(z, w, idx_ws, out, lossacc);
    k_nsum   <<<1,                256, 0, stream>>>(out, lossacc, nsum);
    k_neww   <<<KC,               256, 0, stream>>>(out, nsum);
}